// Round 4
// baseline (645.798 us; speedup 1.0000x reference)
//
#include <hip/hip_runtime.h>
#include <cstdint>

typedef __bf16 bf16;
typedef __bf16 bf16x8 __attribute__((ext_vector_type(8)));
typedef float f32x4 __attribute__((ext_vector_type(4)));
typedef __attribute__((address_space(3))) bf16 lds_bf16;

// ---------------- helpers ----------------
__device__ __forceinline__ void gload_lds16(const void* g, void* l) {
  __builtin_amdgcn_global_load_lds(
      (const __attribute__((address_space(1))) unsigned int*)g,
      (__attribute__((address_space(3))) unsigned int*)l, 16, 0, 0);
}

// inline-asm LDS read: invisible to the compiler's waitcnt pass, so no
// auto-inserted vmcnt(0) drains against outstanding global_load_lds DMAs.
// Completion is enforced manually via counted s_waitcnt lgkmcnt(N) +
// sched_barrier(0) (rule #18) before the consuming MFMA cluster.
__device__ __forceinline__ bf16x8 ld_b128(const lds_bf16* p) {
  bf16x8 r;
  asm volatile("ds_read_b128 %0, %1" : "=v"(r) : "v"(p));
  return r;
}

__device__ __forceinline__ float tanh_fast(float x) {
  float ax = fabsf(x);
  float e = __expf(ax + ax);
  float t = 1.0f - 2.0f / (e + 1.0f);
  return x < 0.0f ? -t : t;
}

// ---------------- shifted-tap GEMM, 128^2 tile, R3 barrier-free pipeline ----
// C[m,co] = sum_{cb,tap,cl} A[n][p+tap+shift0][cb*cbCI+cl]*Bt[co][(cb*ntaps+tap)*cbCI+cl]
// R4: ported the verified gemm8_pool (R3) schedule to the 128^2/4-wave
// geometry used by the grid-limited tail GEMMs (1-2 blocks/CU, where the old
// 2-barrier structure fully exposes the vmcnt(0) drain每chunk). Per 64-k tile:
//   read h0 frags (8 asm ds_read) ; stage tile t+1 (8 DMAs -> buf^1) ;
//   read h1 frags (8) ; lgkm(8)->MFMA(h0) x16 ; lgkm(0)->MFMA(h1) x16 ;
//   __syncthreads()  (implicit vmcnt(0) is ~free: newest DMA a full tile old)
// Staging lane-map / XOR swizzle / fragment addressing identical to the
// proven original. LDS 64 KiB (2 blocks/CU).
// MODE: 0 = plain bias+store, 1 = fused maxpool2, 2 = fused similarity score.
template<int MODE>
__global__ __launch_bounds__(256, 2) void gemm_tap(
    const bf16* __restrict__ A, const bf16* __restrict__ Bt,
    const float* __restrict__ bias, bf16* __restrict__ Out,
    const bf16* __restrict__ zp,
    int snA, int logP, int logCI, int shift0, int ntaps, int cbCount,
    int cbCI, int pairs, int Ktot, int COt, int snO,
    const float* __restrict__ uu, const float* __restrict__ mlpb,
    float* __restrict__ outF)
{
  __shared__ __align__(16) bf16 Ab[2][2][4096];   // [buf][khalf][128r x 32e]
  __shared__ __align__(16) bf16 Bb[2][2][4096];
  (void)pairs;
  const int tid  = threadIdx.x;
  const int wave = tid >> 6, lane = tid & 63;
  const int wr = wave >> 1, wc = wave & 1;
  const int m0  = blockIdx.x << 7;
  const int co0 = blockIdx.y << 7;
  const int P     = 1 << logP;
  const int Pmask = P - 1;
  const int CI    = 1 << logCI;
  f32x4 acc[4][4] = {};

  // staging lane map + XOR k-group swizzle (read side matches; rule #21)
  const int rowL = tid >> 2;
  const int kg   = tid & 3;
  const int fOff = ((kg ^ ((rowL + (rowL >> 2)) & 3)) << 3);

  const int mA0 = m0 + rowL,      nA0 = mA0 >> logP, pA0v = mA0 & Pmask;
  const int mA1 = m0 + rowL + 64, nA1 = mA1 >> logP, pA1v = mA1 & Pmask;
  const bf16* baseA0 = A + nA0 * snA + fOff;
  const bf16* baseA1 = A + nA1 * snA + fOff;
  const bf16* baseB0 = Bt + (co0 + rowL) * Ktot + fOff;
  const bf16* baseB1 = Bt + (co0 + rowL + 64) * Ktot + fOff;
  const bf16* zsrc = zp + fOff;

  const int frow  = lane & 15;
  const int rdOff = (((lane >> 4) ^ ((frow + (frow >> 2)) & 3)) << 3);

  const int kpc = cbCI >> 6;             // 64-k tiles per (cb,tap)
  const int NT  = cbCount * ntaps * kpc;
  int s_kc = 0, s_tap = 0, s_cb = 0;     // staging unit counters (uniform)

  auto stageTile = [&](int bfs) {
    int sh  = s_tap + shift0;
    int rA0 = pA0v + sh, rA1 = pA1v + sh;
    int ko  = s_cb * cbCI + (s_kc << 6);
    const bf16* pa0 = ((unsigned)rA0 < (unsigned)P) ? baseA0 + rA0 * CI + ko : zsrc;
    const bf16* pa1 = ((unsigned)rA1 < (unsigned)P) ? baseA1 + rA1 * CI + ko : zsrc;
    const bf16* pb0 = baseB0 + (s_cb * ntaps + s_tap) * cbCI + (s_kc << 6);
    const bf16* pb1 = baseB1 + (s_cb * ntaps + s_tap) * cbCI + (s_kc << 6);
    gload_lds16(pa0,      &Ab[bfs][0][wave * 512]);
    gload_lds16(pa0 + 32, &Ab[bfs][1][wave * 512]);
    gload_lds16(pa1,      &Ab[bfs][0][2048 + wave * 512]);
    gload_lds16(pa1 + 32, &Ab[bfs][1][2048 + wave * 512]);
    gload_lds16(pb0,      &Bb[bfs][0][wave * 512]);
    gload_lds16(pb0 + 32, &Bb[bfs][1][wave * 512]);
    gload_lds16(pb1,      &Bb[bfs][0][2048 + wave * 512]);
    gload_lds16(pb1 + 32, &Bb[bfs][1][2048 + wave * 512]);
    if (++s_kc == kpc) { s_kc = 0; if (++s_tap == ntaps) { s_tap = 0; ++s_cb; } }
  };

  stageTile(0);
  __syncthreads();

  bf16x8 a0[4], a1[4], b0f[4], b1f[4];

#pragma unroll 1
  for (int t = 0; t < NT; ++t) {
    const int buf = t & 1;
#pragma unroll
    for (int i = 0; i < 4; ++i)
      a0[i] = ld_b128((const lds_bf16*)&Ab[buf][0][((wr << 6) + (i << 4) + frow) * 32 + rdOff]);
#pragma unroll
    for (int j = 0; j < 4; ++j)
      b0f[j] = ld_b128((const lds_bf16*)&Bb[buf][0][((wc << 6) + (j << 4) + frow) * 32 + rdOff]);
    if (t + 1 < NT) stageTile(buf ^ 1);
#pragma unroll
    for (int i = 0; i < 4; ++i)
      a1[i] = ld_b128((const lds_bf16*)&Ab[buf][1][((wr << 6) + (i << 4) + frow) * 32 + rdOff]);
#pragma unroll
    for (int j = 0; j < 4; ++j)
      b1f[j] = ld_b128((const lds_bf16*)&Bb[buf][1][((wc << 6) + (j << 4) + frow) * 32 + rdOff]);
    asm volatile("s_waitcnt lgkmcnt(8)" ::: "memory");
    __builtin_amdgcn_sched_barrier(0);
    __builtin_amdgcn_s_setprio(1);
#pragma unroll
    for (int i = 0; i < 4; ++i)
#pragma unroll
      for (int j = 0; j < 4; ++j)
        acc[i][j] = __builtin_amdgcn_mfma_f32_16x16x32_bf16(a0[i], b0f[j], acc[i][j], 0, 0, 0);
    __builtin_amdgcn_s_setprio(0);
    asm volatile("s_waitcnt lgkmcnt(0)" ::: "memory");
    __builtin_amdgcn_sched_barrier(0);
    __builtin_amdgcn_s_setprio(1);
#pragma unroll
    for (int i = 0; i < 4; ++i)
#pragma unroll
      for (int j = 0; j < 4; ++j)
        acc[i][j] = __builtin_amdgcn_mfma_f32_16x16x32_bf16(a1[i], b1f[j], acc[i][j], 0, 0, 0);
    __builtin_amdgcn_s_setprio(0);
    __syncthreads();
  }

  // epilogue: C/D layout col=lane&15, row=(lane>>4)*4+reg  [m89-verified]
  const int colL = lane & 15;
  const int rq   = (lane >> 4) << 2;

  if (MODE == 2) {
    float* scr0 = (float*)&Ab[0][0][0];   // [128][32] = 16 KB = Ab[0]
    float* scr1 = (float*)&Bb[0][0][0];
    const int n = m0 >> logP;             // one n per block (P == 128)
    const int b = n >> 5;
    const float* u0 = uu + b * 128;
    const float* u1 = uu + 1024 + b * 128;
#pragma unroll
    for (int i = 0; i < 4; ++i) {
#pragma unroll
      for (int r = 0; r < 4; ++r) {
        int rowLcl = (wr << 6) + (i << 4) + rq + r;
        float p0 = 0.0f, p1 = 0.0f;
#pragma unroll
        for (int j = 0; j < 4; ++j) {
          int gco = (wc << 6) + (j << 4) + colL;
          float v = acc[i][j][r];
          p0 += v * u0[gco];
          p1 += v * u1[gco];
        }
        scr0[rowLcl * 32 + (wc << 4) + colL] = p0;
        scr1[rowLcl * 32 + (wc << 4) + colL] = p1;
      }
    }
    __syncthreads();
    {
      int rowLcl = tid >> 1, c = tid & 1;
      const float* s = c ? scr1 : scr0;
      float sum = 0.0f;
#pragma unroll
      for (int k = 0; k < 32; ++k) sum += s[rowLcl * 32 + k];
      float val = 1.0f / (1.0f + __expf(-(sum + mlpb[0])));
      outF[(c ? 32768 : 0) + m0 + rowLcl] = val;
    }
    return;
  }

#pragma unroll
  for (int i = 0; i < 4; ++i) {
    int m = m0 + (wr << 6) + (i << 4) + rq;
    int n = m >> logP, p = m & Pmask;
#pragma unroll
    for (int j = 0; j < 4; ++j) {
      int gco = co0 + (wc << 6) + (j << 4) + colL;
      float bv = bias[gco];
      if (MODE == 1) {
        float v0 = fmaxf(acc[i][j][0], acc[i][j][1]) + bv;
        float v1 = fmaxf(acc[i][j][2], acc[i][j][3]) + bv;
        bf16* o = Out + n * snO + (p >> 1) * COt + gco;
        o[0]   = (bf16)v0;
        o[COt] = (bf16)v1;
      } else {
#pragma unroll
        for (int r = 0; r < 4; ++r)
          Out[n * snO + (p + r) * COt + gco] = (bf16)(acc[i][j][r] + bv);
      }
    }
  }
}

// ---------------- 256x256-tile barrier-free-inner pipelined GEMM -----------
// R3 structure (verified): all 8 staging DMAs for tile t+1 issue at the TOP
// of tile t into buf^1; one __syncthreads() per tile; counted lgkmcnt within.
template<int LOGP, int LOGCI, int SH0, int NTAPS, int CBCNT, int CBCI>
__global__ __launch_bounds__(512, 2) void gemm8_pool(
    const bf16* __restrict__ A, const bf16* __restrict__ Bt,
    const float* __restrict__ bias, bf16* __restrict__ Out,
    const bf16* __restrict__ zp, int snA, int Ktot, int COt, int snO)
{
  __shared__ __align__(16) bf16 Ab[2][2][8192];
  __shared__ __align__(16) bf16 Bb[2][2][8192];
  constexpr int P = 1 << LOGP, CI = 1 << LOGCI;
  constexpr int KPC = CBCI / 64;
  constexpr int NT = CBCNT * NTAPS * KPC;

  const int tid = threadIdx.x;
  const int wave = tid >> 6, lane = tid & 63;
  const int wr = wave >> 2, wc = wave & 3;
  const int m0 = blockIdx.x << 8, co0 = blockIdx.y << 8;
  const int n0 = m0 >> LOGP;

  f32x4 acc[8][4] = {};

  const int rowP = tid >> 2;
  const int kOff = (((tid & 3) ^ ((rowP + (rowP >> 2)) & 3)) << 3);
  const bf16* baseA = A + n0 * snA + kOff;
  const bf16* pBs   = Bt + (co0 + rowP) * Ktot + kOff;
  const bf16* zsrc  = zp + kOff;
  const int ldsW = wave << 9;   // per-wave staging base (elems) = wave*1KB
  const int bStride = 128 * Ktot;

  const int frow = lane & 15;
  const int rdOff = (((lane >> 4) ^ ((frow + (frow >> 2)) & 3)) << 3);

  int s_kc = 0, s_tap = 0, s_cb = 0;   // staging unit counters (uniform)

  auto stageTile = [&](int bfs) {
    int rA = rowP + s_tap + SH0;
    bool v = (unsigned)rA < (unsigned)P;
    const bf16* pA0 = v ? baseA + rA * CI + (s_cb * CBCI + s_kc * 64) : zsrc;
    const bf16* pA1 = v ? pA0 + snA : zsrc;
    gload_lds16(pA0,      &Ab[bfs][0][ldsW]);
    gload_lds16(pA0 + 32, &Ab[bfs][1][ldsW]);
    gload_lds16(pA1,      &Ab[bfs][0][ldsW + 4096]);
    gload_lds16(pA1 + 32, &Ab[bfs][1][ldsW + 4096]);
    gload_lds16(pBs,                &Bb[bfs][0][ldsW]);
    gload_lds16(pBs + 32,           &Bb[bfs][1][ldsW]);
    gload_lds16(pBs + bStride,      &Bb[bfs][0][ldsW + 4096]);
    gload_lds16(pBs + bStride + 32, &Bb[bfs][1][ldsW + 4096]);
    pBs += 64;
    if (++s_kc == KPC) { s_kc = 0; if (++s_tap == NTAPS) { s_tap = 0; ++s_cb; } }
  };

  auto ldA = [&](int buf, int ks, int mh, int i) {
    return ld_b128((const lds_bf16*)
        &Ab[buf][ks][((wr << 7) + (mh << 6) + (i << 4) + frow) * 32 + rdOff]);
  };
  auto ldB = [&](int buf, int ks, int j) {
    return ld_b128((const lds_bf16*)
        &Bb[buf][ks][((wc << 6) + (j << 4) + frow) * 32 + rdOff]);
  };

  stageTile(0);
  __syncthreads();

  bf16x8 a0[4], a1[4], b0[4], b1[4];

#pragma unroll 1
  for (int t = 0; t < NT; ++t) {
    const int buf = t & 1;
#pragma unroll
    for (int i = 0; i < 4; ++i) a0[i] = ldA(buf, 0, 0, i);
#pragma unroll
    for (int j = 0; j < 4; ++j) b0[j] = ldB(buf, 0, j);
    if (t + 1 < NT) stageTile(buf ^ 1);
#pragma unroll
    for (int i = 0; i < 4; ++i) a1[i] = ldA(buf, 0, 1, i);
    asm volatile("s_waitcnt lgkmcnt(4)" ::: "memory");
    __builtin_amdgcn_sched_barrier(0);
    __builtin_amdgcn_s_setprio(1);
#pragma unroll
    for (int i = 0; i < 4; ++i)
#pragma unroll
      for (int j = 0; j < 4; ++j)
        acc[i][j] = __builtin_amdgcn_mfma_f32_16x16x32_bf16(a0[i], b0[j], acc[i][j], 0, 0, 0);
    __builtin_amdgcn_s_setprio(0);
#pragma unroll
    for (int i = 0; i < 4; ++i) a0[i] = ldA(buf, 1, 0, i);
#pragma unroll
    for (int j = 0; j < 4; ++j) b1[j] = ldB(buf, 1, j);
    asm volatile("s_waitcnt lgkmcnt(8)" ::: "memory");
    __builtin_amdgcn_sched_barrier(0);
    __builtin_amdgcn_s_setprio(1);
#pragma unroll
    for (int i = 0; i < 4; ++i)
#pragma unroll
      for (int j = 0; j < 4; ++j)
        acc[4 + i][j] = __builtin_amdgcn_mfma_f32_16x16x32_bf16(a1[i], b0[j], acc[4 + i][j], 0, 0, 0);
    __builtin_amdgcn_s_setprio(0);
#pragma unroll
    for (int i = 0; i < 4; ++i) a1[i] = ldA(buf, 1, 1, i);
    asm volatile("s_waitcnt lgkmcnt(4)" ::: "memory");
    __builtin_amdgcn_sched_barrier(0);
    __builtin_amdgcn_s_setprio(1);
#pragma unroll
    for (int i = 0; i < 4; ++i)
#pragma unroll
      for (int j = 0; j < 4; ++j)
        acc[i][j] = __builtin_amdgcn_mfma_f32_16x16x32_bf16(a0[i], b1[j], acc[i][j], 0, 0, 0);
    __builtin_amdgcn_s_setprio(0);
    asm volatile("s_waitcnt lgkmcnt(0)" ::: "memory");
    __builtin_amdgcn_sched_barrier(0);
    __builtin_amdgcn_s_setprio(1);
#pragma unroll
    for (int i = 0; i < 4; ++i)
#pragma unroll
      for (int j = 0; j < 4; ++j)
        acc[4 + i][j] = __builtin_amdgcn_mfma_f32_16x16x32_bf16(a1[i], b1[j], acc[4 + i][j], 0, 0, 0);
    __builtin_amdgcn_s_setprio(0);
    __syncthreads();
  }

  // epilogue: fused maxpool2; C/D col=lane&15, row=(lane>>4)*4+reg
  const int colL = lane & 15, rq = (lane >> 4) << 2;
#pragma unroll
  for (int i = 0; i < 8; ++i) {
    int m = m0 + (wr << 7) + (i << 4) + rq;
    int n = m >> LOGP, p = m & (P - 1);
    bf16* orow = Out + n * snO + (p >> 1) * COt;
#pragma unroll
    for (int j = 0; j < 4; ++j) {
      int gco = co0 + (wc << 6) + (j << 4) + colL;
      float bv = bias[gco];
      orow[gco]       = (bf16)(fmaxf(acc[i][j][0], acc[i][j][1]) + bv);
      orow[COt + gco] = (bf16)(fmaxf(acc[i][j][2], acc[i][j][3]) + bv);
    }
  }
}

// ---------------- fused prep: weights + biases + cq/uu + batch cvt ----------
__global__ __launch_bounds__(256) void prep_all(
    const float* __restrict__ conv1_w, const float* __restrict__ conv2_w,
    const float* __restrict__ sa_wq, const float* __restrict__ sa_wk,
    const float* __restrict__ ca_wk, const float* __restrict__ dc1_w,
    const float* __restrict__ dc2_w, const float* __restrict__ sim1_w,
    const float* __restrict__ c1b, const float* __restrict__ c2b,
    const float* __restrict__ sabq, const float* __restrict__ sabk,
    const float* __restrict__ cabk, const float* __restrict__ d1b,
    const float* __restrict__ d2b,
    const float* __restrict__ c1, const float* __restrict__ c2,
    const float* __restrict__ ca_wq, const float* __restrict__ ca_bq,
    const float* __restrict__ sim2_w, const float* __restrict__ mlp_w,
    const float* __restrict__ batch, bf16* __restrict__ bb16,
    bf16* __restrict__ Bt1, bf16* __restrict__ Bt2, bf16* __restrict__ Bqkc,
    bf16* __restrict__ Btd1, bf16* __restrict__ Btd2, bf16* __restrict__ Bts1,
    float* __restrict__ bias, float* __restrict__ cq, float* __restrict__ uu)
{
  const int blk = blockIdx.x;
  if (blk >= 27492) {
    int idx = ((blk - 27492) * 256 + threadIdx.x) * 8;
    float4 a = *(const float4*)&batch[idx];
    float4 b = *(const float4*)&batch[idx + 4];
    bf16x8 v;
    v[0] = (bf16)a.x; v[1] = (bf16)a.y; v[2] = (bf16)a.z; v[3] = (bf16)a.w;
    v[4] = (bf16)b.x; v[5] = (bf16)b.y; v[6] = (bf16)b.z; v[7] = (bf16)b.w;
    *(bf16x8*)&bb16[idx] = v;
    return;
  }
  if (blk < 27468) {
    int idx = blk * 256 + threadIdx.x;
    if (idx < 3072) {
      if (idx < 2944) {
        float v;
        if (idx < 512)       v = c1b[idx];
        else if (idx < 768)  v = c2b[idx - 512];
        else if (idx < 1024) v = sabq[idx - 768];
        else if (idx < 1280) v = sabk[idx - 1024];
        else if (idx < 1536) v = cabk[idx - 1280];
        else if (idx < 2560) v = d1b[(idx - 1536) & 511];
        else if (idx < 2816) v = d2b[(idx - 2560) & 127];
        else                 v = 0.0f;
        bias[idx] = v;
      }
    } else if (idx < 2624512) {
      int i = idx - 3072;
      int co = i / 5120, r = i - co * 5120;
      int cb = r / 1280, r2 = r - cb * 1280;
      int tap = r2 >> 8, cl = r2 & 255;
      Bt1[i] = (bf16)conv1_w[co * 5120 + (cb * 256 + cl) * 5 + tap];
    } else if (idx < 3279872) {
      int i = idx - 2624512;
      int co = i / 2560, r = i - co * 2560;
      int cb = r / 1280, r2 = r - cb * 1280;
      int tap = r2 >> 8, cl = r2 & 255;
      Bt2[i] = (bf16)conv2_w[co * 2560 + (cb * 256 + cl) * 5 + tap];
    } else if (idx < 3476480) {
      int i = idx - 3279872;
      int co = i >> 8, ci = i & 255;
      float v;
      if (co < 256)      v = sa_wq[ci * 256 + co];
      else if (co < 512) v = sa_wk[ci * 256 + (co - 256)];
      else               v = ca_wk[ci * 256 + (co - 512)];
      Bqkc[i] = (bf16)v;
    } else if (idx < 6622208) {
      int i = idx - 3476480;
      int co = i / 3072, r = i - co * 3072;
      int cb = r / 768, r2 = r - cb * 768;
      int tap = r2 >> 8, cl = r2 & 255;
      int ci = cb * 256 + cl;
      int par = co >> 9, c = co & 511;
      int ki = -1;
      if (par == 0) { if (tap == 1) ki = 1; else if (tap == 0) ki = 3; }
      else          { if (tap == 2) ki = 0; else if (tap == 1) ki = 2; }
      Btd1[i] = (ki >= 0) ? (bf16)dc1_w[ci * 2048 + c * 4 + ki] : (bf16)0.0f;
    } else if (idx < 7015424) {
      int i = idx - 6622208;
      int co = i / 1536, r = i - co * 1536;
      int cb = r / 768, r2 = r - cb * 768;
      int tap = r2 >> 8, cl = r2 & 255;
      int ci = cb * 256 + cl;
      int par = co >> 7, c = co & 127;
      int ki = -1;
      if (par == 0) { if (tap == 1) ki = 1; else if (tap == 0) ki = 3; }
      else          { if (tap == 2) ki = 0; else if (tap == 1) ki = 2; }
      Btd2[i] = (ki >= 0) ? (bf16)dc2_w[ci * 512 + c * 4 + ki] : (bf16)0.0f;
    } else {
      int i = idx - 7015424;
      int co = i >> 7, ci = i & 127;
      Bts1[i] = (bf16)sim1_w[ci * 128 + co];
    }
  } else {
    int sub = blk - 27468;
    if (sub < 16) {
      int o = sub * 256 + threadIdx.x;
      int c = o >> 11, b = (o >> 8) & 7, h = o & 255;
      const float* cc = (c ? c2 : c1) + b * 300;
      float acc = ca_bq[h];
      for (int j = 0; j < 300; ++j)
        acc += cc[j] * ca_wq[j * 256 + h];
      cq[o] = acc;
    } else {
      int o = (sub - 16) * 256 + threadIdx.x;
      int c = o >> 10, b = (o >> 7) & 7, m = o & 127;
      const float* cc = (c ? c2 : c1) + b * 300;
      float acc = 0.0f;
      for (int j = 0; j < 300; ++j)
        acc += cc[j] * sim2_w[j * 128 + m];
      uu[o] = acc * mlp_w[m];
    }
  }
}

// ---------------- fused additive attention (one block per n) ----------------
__global__ __launch_bounds__(256) void kattn(
    const bf16* __restrict__ tmp2, const bf16* __restrict__ qkc,
    const float* __restrict__ sa_v, const float* __restrict__ sa_vb,
    const float* __restrict__ ca_v, const float* __restrict__ ca_vb,
    const float* __restrict__ cq, const int* __restrict__ seg,
    bf16* __restrict__ ar)
{
  const int n = blockIdx.x, tid = threadIdx.x;
  __shared__ __align__(16) bf16 t2[32 * 264];
  __shared__ __align__(16) bf16 bufA[32 * 264];
  __shared__ __align__(16) bf16 bufB[32 * 264];
  __shared__ float sv_s[256], cv_s[256];
  __shared__ float sbc[66];
  __shared__ float sbs[32 * 33];
  const int sl = seg[n];

#pragma unroll
  for (int rr = 0; rr < 4; ++rr) {
    int q = tid + (rr << 8);
    int k = q >> 5, c8 = (q & 31) << 3;
    *(uint4*)&t2[k * 264 + c8]   = *(const uint4*)&tmp2[n * 8192 + k * 256 + c8];
    *(uint4*)&bufA[k * 264 + c8] = *(const uint4*)&qkc[n * 24576 + k * 768 + 512 + c8];
  }
  sv_s[tid] = sa_v[tid];
  cv_s[tid] = ca_v[tid];
  __syncthreads();

  if (tid < 64) {
    int c = tid >> 5, k = tid & 31;
    const float* cqr = cq + (c * 8 + (n >> 5)) * 256;
    float acc = 0.0f;
    for (int h = 0; h < 256; ++h)
      acc += tanh_fast(cqr[h] + (float)bufA[k * 264 + h]) * cv_s[h];
    float sc = acc + ca_vb[0];
    sbc[c * 33 + k] = (sl > (k << 2)) ? sc : -1e9f;
  }
  __syncthreads();

#pragma unroll
  for (int rr = 0; rr < 4; ++rr) {
    int q = tid + (rr << 8);
    int k = q >> 5, c8 = (q & 31) << 3;
    *(uint4*)&bufB[k * 264 + c8] = *(const uint4*)&qkc[n * 24576 + k * 768 + c8];
    *(uint4*)&bufA[k * 264 + c8] = *(const uint4*)&qkc[n * 24576 + k * 768 + 256 + c8];
  }
  if (tid < 2) {
    float* row = &sbc[tid * 33];
    float mx = -1e30f;
    for (int k = 0; k < 32; ++k) mx = fmaxf(mx, row[k]);
    float sum = 0.0f;
    for (int k = 0; k < 32; ++k) { float e = __expf(row[k] - mx); row[k] = e; sum += e; }
    float inv = 1.0f / sum;
    for (int k = 0; k < 32; ++k) row[k] *= inv;
  }
  __syncthreads();

  {
    int col = tid;
    float rr0 = 0.0f, rr1 = 0.0f;
    for (int k = 0; k < 32; ++k) {
      float tv = (float)t2[k * 264 + col];
      rr0 += sbc[k] * tv;
      rr1 += sbc[33 + k] * tv;
    }
    bf16 b0 = (bf16)rr0, b1 = (bf16)rr1;
    bf16* arn = ar + n * 32768;
    for (int q = 0; q < 32; ++q) {
      arn[q * 1024 + col]       = t2[q * 264 + col];
      arn[q * 1024 + 512 + col] = b0;
      arn[q * 1024 + 768 + col] = b1;
    }
  }
  {
    float svb = sa_vb[0];
#pragma unroll
    for (int rr = 0; rr < 4; ++rr) {
      int id = tid + (rr << 8);
      int q = id >> 5, k = id & 31;
      float acc = 0.0f;
      for (int h = 0; h < 256; ++h)
        acc += tanh_fast((float)bufB[q * 264 + h] + (float)bufA[k * 264 + h]) * sv_s[h];
      float sc = acc + svb;
      sbs[q * 33 + k] = (sl > (k << 2)) ? sc : -1e9f;
    }
  }
  __syncthreads();

  if (tid < 32) {
    float* row = &sbs[tid * 33];
    float mx = -1e30f;
    for (int k = 0; k < 32; ++k) mx = fmaxf(mx, row[k]);
    float sum = 0.0f;
    for (int k = 0; k < 32; ++k) { float e = __expf(row[k] - mx); row[k] = e; sum += e; }
    float inv = 1.0f / sum;
    for (int k = 0; k < 32; ++k) row[k] *= inv;
  }
  __syncthreads();

  {
    int col = tid;
    bf16* arn = ar + n * 32768;
    for (int q = 0; q < 32; ++q) {
      float acc = 0.0f;
      for (int k = 0; k < 32; ++k)
        acc += sbs[q * 33 + k] * (float)t2[k * 264 + col];
      arn[q * 1024 + 256 + col] = (bf16)acc;
    }
  }
}

// ---------------- launch ----------------
extern "C" void kernel_launch(void* const* d_in, const int* in_sizes, int n_in,
                              void* d_out, int out_size, void* d_ws, size_t ws_size,
                              hipStream_t stream) {
  const float* batch    = (const float*)d_in[0];
  const float* concept1 = (const float*)d_in[1];
  const float* concept2 = (const float*)d_in[2];
  const int*   seg      = (const int*)d_in[3];
  const float* conv1_w  = (const float*)d_in[4];
  const float* conv1_b  = (const float*)d_in[5];
  const float* conv2_w  = (const float*)d_in[6];
  const float* conv2_b  = (const float*)d_in[7];
  const float* sa_wq    = (const float*)d_in[8];
  const float* sa_bq    = (const float*)d_in[9];
  const float* sa_wk    = (const float*)d_in[10];
  const float* sa_bk    = (const float*)d_in[11];
  const float* sa_v     = (const float*)d_in[12];
  const float* sa_vb    = (const float*)d_in[13];
  const float* ca_wq    = (const float*)d_in[14];
  const float* ca_bq    = (const float*)d_in[15];
  const float* ca_wk    = (const float*)d_in[16];
  const float* ca_bk    = (const float*)d_in[17];
  const float* ca_v     = (const float*)d_in[18];
  const float* ca_vb    = (const float*)d_in[19];
  const float* dc1_w    = (const float*)d_in[20];
  const float* dc1_b    = (const float*)d_in[21];
  const float* dc2_w    = (const float*)d_in[22];
  const float* dc2_b    = (const float*)d_in[23];
  const float* sim1_w   = (const float*)d_in[24];
  const float* sim2_w   = (const float*)d_in[25];
  const float* mlp_w    = (const float*)d_in[26];
  const float* mlp_b    = (const float*)d_in[27];

  char* ws = (char*)d_ws;
  bf16* bb16  = (bf16*)(ws + 0);
  bf16* qkcb  = (bf16*)(ws + 0);
  bf16* arb   = (bf16*)(ws + 12582912);
  bf16* d1    = (bf16*)(ws + 29360128);
  bf16* rbuf  = (bf16*)(ws + 46137344);
  bf16* t1    = (bf16*)(ws + 67108864);
  bf16* tmp2b = (bf16*)(ws + 83886080);
  bf16* Bt1   = (bf16*)(ws + 88080384);
  bf16* Bt2   = (bf16*)(ws + 93323264);
  bf16* Bqkc  = (bf16*)(ws + 94633984);
  bf16* Btd1  = (bf16*)(ws + 95027200);
  bf16* Btd2  = (bf16*)(ws + 101318656);
  bf16* Bts1  = (bf16*)(ws + 102105088);
  float* biasall = (float*)(ws + 102137856);
  float* cqb  = (float*)(ws + 102149632);
  float* uub  = (float*)(ws + 102166016);
  const bf16* zp = (const bf16*)(biasall + 2816);  // 128 f32 zeros = 256 bf16 zeros
  float* outp = (float*)d_out;

  prep_all<<<43876, 256, 0, stream>>>(
      conv1_w, conv2_w, sa_wq, sa_wk, ca_wk, dc1_w, dc2_w, sim1_w,
      conv1_b, conv2_b, sa_bq, sa_bk, ca_bk, dc1_b, dc2_b,
      concept1, concept2, ca_wq, ca_bq, sim2_w, mlp_w,
      batch, bb16,
      Bt1, Bt2, Bqkc, Btd1, Btd2, Bts1, biasall, cqb, uub);

  // conv1 + pool: 256^2-tile barrier-free-inner pipeline -> t1 [256][64][512]
  gemm8_pool<7, 10, -2, 5, 4, 256><<<dim3(128, 2), 512, 0, stream>>>(
      bb16, Bt1, biasall + 0, t1, zp, 131072, 5120, 512, 32768);

  // conv2 + pool: pipelined 128^2 -> tmp2 [256][32][256]
  gemm_tap<1><<<dim3(128, 2), 256, 0, stream>>>(
      t1, Bt2, biasall + 512, tmp2b, zp, 32768, 6, 9, -2, 5, 2, 256, 4, 2560, 256, 8192,
      nullptr, nullptr, nullptr);

  // fused q/k/ck projection -> qkc [256][32][768]
  gemm_tap<0><<<dim3(64, 6), 256, 0, stream>>>(
      tmp2b, Bqkc, biasall + 768, qkcb, zp, 8192, 5, 8, 0, 1, 1, 256, 4, 256, 768, 24576,
      nullptr, nullptr, nullptr);

  // attention -> ar [256][32][1024]
  kattn<<<256, 256, 0, stream>>>(tmp2b, qkcb, sa_v, sa_vb, ca_v, ca_vb, cqb, seg, arb);

  // deconv1 -> d1 [256][64][1024] (parity-interleaved)
  gemm_tap<0><<<dim3(64, 8), 256, 0, stream>>>(
      arb, Btd1, biasall + 1536, d1, zp, 32768, 5, 10, -1, 3, 4, 256, 4, 3072, 1024, 32768,
      nullptr, nullptr, nullptr);

  // deconv2 -> rbuf [256][64][256] (parity-interleaved)
  gemm_tap<0><<<dim3(128, 2), 256, 0, stream>>>(
      d1, Btd2, biasall + 2560, rbuf, zp, 32768, 6, 9, -1, 3, 2, 256, 4, 1536, 256, 16384,
      nullptr, nullptr, nullptr);

  // sim1 + fused score -> out (fp32, both concepts)
  gemm_tap<2><<<dim3(256, 1), 256, 0, stream>>>(
      rbuf, Bts1, biasall + 2816, nullptr, zp, 16384, 7, 7, 0, 1, 1, 128, 2, 128, 128, 16384,
      uub, mlp_b, outp);
}

// Round 5
// 617.112 us; speedup vs baseline: 1.0465x; 1.0465x over previous
//
#include <hip/hip_runtime.h>
#include <cstdint>

typedef __bf16 bf16;
typedef __bf16 bf16x8 __attribute__((ext_vector_type(8)));
typedef float f32x4 __attribute__((ext_vector_type(4)));
typedef __attribute__((address_space(3))) bf16 lds_bf16;

// ---------------- helpers ----------------
__device__ __forceinline__ void gload_lds16(const void* g, void* l) {
  __builtin_amdgcn_global_load_lds(
      (const __attribute__((address_space(1))) unsigned int*)g,
      (__attribute__((address_space(3))) unsigned int*)l, 16, 0, 0);
}

// inline-asm LDS read: invisible to the compiler's waitcnt pass, so no
// auto-inserted vmcnt(0) drains against outstanding global_load_lds DMAs.
// Completion is enforced manually via counted s_waitcnt lgkmcnt(N) +
// sched_barrier(0) (rule #18) before the consuming MFMA cluster.
__device__ __forceinline__ bf16x8 ld_b128(const lds_bf16* p) {
  bf16x8 r;
  asm volatile("ds_read_b128 %0, %1" : "=v"(r) : "v"(p));
  return r;
}

__device__ __forceinline__ float tanh_fast(float x) {
  float ax = fabsf(x);
  float e = __expf(ax + ax);
  float t = 1.0f - 2.0f / (e + 1.0f);
  return x < 0.0f ? -t : t;
}

// ---------------- shifted-tap GEMM, 128^2 tile, barrier-free pipeline -------
// R5: wave-staggered k-half order. Odd waves consume (k1,k0), even waves
// (k0,k1) — accumulation over k is commutative into the same fp32 acc, LDS
// reads are read-only within the tile, so this only de-phases the waves:
// half the block MFMAs one k-half while the other half issues ds_reads for
// the other, overlapping the LDS pipe with the matrix pipe instead of
// barrier-aligned take-turns bursts.
// MODE: 0 = plain bias+store, 1 = fused maxpool2, 2 = fused similarity score.
template<int MODE>
__global__ __launch_bounds__(256, 2) void gemm_tap(
    const bf16* __restrict__ A, const bf16* __restrict__ Bt,
    const float* __restrict__ bias, bf16* __restrict__ Out,
    const bf16* __restrict__ zp,
    int snA, int logP, int logCI, int shift0, int ntaps, int cbCount,
    int cbCI, int pairs, int Ktot, int COt, int snO,
    const float* __restrict__ uu, const float* __restrict__ mlpb,
    float* __restrict__ outF)
{
  __shared__ __align__(16) bf16 Ab[2][2][4096];   // [buf][khalf][128r x 32e]
  __shared__ __align__(16) bf16 Bb[2][2][4096];
  (void)pairs;
  const int tid  = threadIdx.x;
  const int wave = tid >> 6, lane = tid & 63;
  const int wr = wave >> 1, wc = wave & 1;
  const int m0  = blockIdx.x << 7;
  const int co0 = blockIdx.y << 7;
  const int P     = 1 << logP;
  const int Pmask = P - 1;
  const int CI    = 1 << logCI;
  f32x4 acc[4][4] = {};

  // staging lane map + XOR k-group swizzle (read side matches; rule #21)
  const int rowL = tid >> 2;
  const int kg   = tid & 3;
  const int fOff = ((kg ^ ((rowL + (rowL >> 2)) & 3)) << 3);

  const int mA0 = m0 + rowL,      nA0 = mA0 >> logP, pA0v = mA0 & Pmask;
  const int mA1 = m0 + rowL + 64, nA1 = mA1 >> logP, pA1v = mA1 & Pmask;
  const bf16* baseA0 = A + nA0 * snA + fOff;
  const bf16* baseA1 = A + nA1 * snA + fOff;
  const bf16* baseB0 = Bt + (co0 + rowL) * Ktot + fOff;
  const bf16* baseB1 = Bt + (co0 + rowL + 64) * Ktot + fOff;
  const bf16* zsrc = zp + fOff;

  const int frow  = lane & 15;
  const int rdOff = (((lane >> 4) ^ ((frow + (frow >> 2)) & 3)) << 3);

  const int ksA = wave & 1, ksB = ksA ^ 1;   // per-wave k-half order

  const int kpc = cbCI >> 6;             // 64-k tiles per (cb,tap)
  const int NT  = cbCount * ntaps * kpc;
  int s_kc = 0, s_tap = 0, s_cb = 0;     // staging unit counters (uniform)

  auto stageTile = [&](int bfs) {
    int sh  = s_tap + shift0;
    int rA0 = pA0v + sh, rA1 = pA1v + sh;
    int ko  = s_cb * cbCI + (s_kc << 6);
    const bf16* pa0 = ((unsigned)rA0 < (unsigned)P) ? baseA0 + rA0 * CI + ko : zsrc;
    const bf16* pa1 = ((unsigned)rA1 < (unsigned)P) ? baseA1 + rA1 * CI + ko : zsrc;
    const bf16* pb0 = baseB0 + (s_cb * ntaps + s_tap) * cbCI + (s_kc << 6);
    const bf16* pb1 = baseB1 + (s_cb * ntaps + s_tap) * cbCI + (s_kc << 6);
    gload_lds16(pa0,      &Ab[bfs][0][wave * 512]);
    gload_lds16(pa0 + 32, &Ab[bfs][1][wave * 512]);
    gload_lds16(pa1,      &Ab[bfs][0][2048 + wave * 512]);
    gload_lds16(pa1 + 32, &Ab[bfs][1][2048 + wave * 512]);
    gload_lds16(pb0,      &Bb[bfs][0][wave * 512]);
    gload_lds16(pb0 + 32, &Bb[bfs][1][wave * 512]);
    gload_lds16(pb1,      &Bb[bfs][0][2048 + wave * 512]);
    gload_lds16(pb1 + 32, &Bb[bfs][1][2048 + wave * 512]);
    if (++s_kc == kpc) { s_kc = 0; if (++s_tap == ntaps) { s_tap = 0; ++s_cb; } }
  };

  stageTile(0);
  __syncthreads();

  bf16x8 a0[4], a1[4], b0f[4], b1f[4];

#pragma unroll 1
  for (int t = 0; t < NT; ++t) {
    const int buf = t & 1;
#pragma unroll
    for (int i = 0; i < 4; ++i)
      a0[i] = ld_b128((const lds_bf16*)&Ab[buf][ksA][((wr << 6) + (i << 4) + frow) * 32 + rdOff]);
#pragma unroll
    for (int j = 0; j < 4; ++j)
      b0f[j] = ld_b128((const lds_bf16*)&Bb[buf][ksA][((wc << 6) + (j << 4) + frow) * 32 + rdOff]);
    if (t + 1 < NT) stageTile(buf ^ 1);
#pragma unroll
    for (int i = 0; i < 4; ++i)
      a1[i] = ld_b128((const lds_bf16*)&Ab[buf][ksB][((wr << 6) + (i << 4) + frow) * 32 + rdOff]);
#pragma unroll
    for (int j = 0; j < 4; ++j)
      b1f[j] = ld_b128((const lds_bf16*)&Bb[buf][ksB][((wc << 6) + (j << 4) + frow) * 32 + rdOff]);
    asm volatile("s_waitcnt lgkmcnt(8)" ::: "memory");
    __builtin_amdgcn_sched_barrier(0);
    __builtin_amdgcn_s_setprio(1);
#pragma unroll
    for (int i = 0; i < 4; ++i)
#pragma unroll
      for (int j = 0; j < 4; ++j)
        acc[i][j] = __builtin_amdgcn_mfma_f32_16x16x32_bf16(a0[i], b0f[j], acc[i][j], 0, 0, 0);
    __builtin_amdgcn_s_setprio(0);
    asm volatile("s_waitcnt lgkmcnt(0)" ::: "memory");
    __builtin_amdgcn_sched_barrier(0);
    __builtin_amdgcn_s_setprio(1);
#pragma unroll
    for (int i = 0; i < 4; ++i)
#pragma unroll
      for (int j = 0; j < 4; ++j)
        acc[i][j] = __builtin_amdgcn_mfma_f32_16x16x32_bf16(a1[i], b1f[j], acc[i][j], 0, 0, 0);
    __builtin_amdgcn_s_setprio(0);
    __syncthreads();
  }

  // epilogue: C/D layout col=lane&15, row=(lane>>4)*4+reg  [m89-verified]
  const int colL = lane & 15;
  const int rq   = (lane >> 4) << 2;

  if (MODE == 2) {
    float* scr0 = (float*)&Ab[0][0][0];   // [128][32] = 16 KB = Ab[0]
    float* scr1 = (float*)&Bb[0][0][0];
    const int n = m0 >> logP;             // one n per block (P == 128)
    const int b = n >> 5;
    const float* u0 = uu + b * 128;
    const float* u1 = uu + 1024 + b * 128;
#pragma unroll
    for (int i = 0; i < 4; ++i) {
#pragma unroll
      for (int r = 0; r < 4; ++r) {
        int rowLcl = (wr << 6) + (i << 4) + rq + r;
        float p0 = 0.0f, p1 = 0.0f;
#pragma unroll
        for (int j = 0; j < 4; ++j) {
          int gco = (wc << 6) + (j << 4) + colL;
          float v = acc[i][j][r];
          p0 += v * u0[gco];
          p1 += v * u1[gco];
        }
        scr0[rowLcl * 32 + (wc << 4) + colL] = p0;
        scr1[rowLcl * 32 + (wc << 4) + colL] = p1;
      }
    }
    __syncthreads();
    {
      int rowLcl = tid >> 1, c = tid & 1;
      const float* s = c ? scr1 : scr0;
      float sum = 0.0f;
#pragma unroll
      for (int k = 0; k < 32; ++k) sum += s[rowLcl * 32 + k];
      float val = 1.0f / (1.0f + __expf(-(sum + mlpb[0])));
      outF[(c ? 32768 : 0) + m0 + rowLcl] = val;
    }
    return;
  }

#pragma unroll
  for (int i = 0; i < 4; ++i) {
    int m = m0 + (wr << 6) + (i << 4) + rq;
    int n = m >> logP, p = m & Pmask;
#pragma unroll
    for (int j = 0; j < 4; ++j) {
      int gco = co0 + (wc << 6) + (j << 4) + colL;
      float bv = bias[gco];
      if (MODE == 1) {
        float v0 = fmaxf(acc[i][j][0], acc[i][j][1]) + bv;
        float v1 = fmaxf(acc[i][j][2], acc[i][j][3]) + bv;
        bf16* o = Out + n * snO + (p >> 1) * COt + gco;
        o[0]   = (bf16)v0;
        o[COt] = (bf16)v1;
      } else {
#pragma unroll
        for (int r = 0; r < 4; ++r)
          Out[n * snO + (p + r) * COt + gco] = (bf16)(acc[i][j][r] + bv);
      }
    }
  }
}

// ---------------- 256x256-tile barrier-free-inner pipelined GEMM -----------
// R3 structure + R5 wave-staggered k-half order (odd waves k1->k0).
template<int LOGP, int LOGCI, int SH0, int NTAPS, int CBCNT, int CBCI>
__global__ __launch_bounds__(512, 2) void gemm8_pool(
    const bf16* __restrict__ A, const bf16* __restrict__ Bt,
    const float* __restrict__ bias, bf16* __restrict__ Out,
    const bf16* __restrict__ zp, int snA, int Ktot, int COt, int snO)
{
  __shared__ __align__(16) bf16 Ab[2][2][8192];
  __shared__ __align__(16) bf16 Bb[2][2][8192];
  constexpr int P = 1 << LOGP, CI = 1 << LOGCI;
  constexpr int KPC = CBCI / 64;
  constexpr int NT = CBCNT * NTAPS * KPC;

  const int tid = threadIdx.x;
  const int wave = tid >> 6, lane = tid & 63;
  const int wr = wave >> 2, wc = wave & 3;
  const int m0 = blockIdx.x << 8, co0 = blockIdx.y << 8;
  const int n0 = m0 >> LOGP;

  f32x4 acc[8][4] = {};

  const int rowP = tid >> 2;
  const int kOff = (((tid & 3) ^ ((rowP + (rowP >> 2)) & 3)) << 3);
  const bf16* baseA = A + n0 * snA + kOff;
  const bf16* pBs   = Bt + (co0 + rowP) * Ktot + kOff;
  const bf16* zsrc  = zp + kOff;
  const int ldsW = wave << 9;   // per-wave staging base (elems) = wave*1KB
  const int bStride = 128 * Ktot;

  const int frow = lane & 15;
  const int rdOff = (((lane >> 4) ^ ((frow + (frow >> 2)) & 3)) << 3);

  const int ksA = wave & 1, ksB = ksA ^ 1;   // per-wave k-half order

  int s_kc = 0, s_tap = 0, s_cb = 0;   // staging unit counters (uniform)

  auto stageTile = [&](int bfs) {
    int rA = rowP + s_tap + SH0;
    bool v = (unsigned)rA < (unsigned)P;
    const bf16* pA0 = v ? baseA + rA * CI + (s_cb * CBCI + s_kc * 64) : zsrc;
    const bf16* pA1 = v ? pA0 + snA : zsrc;
    gload_lds16(pA0,      &Ab[bfs][0][ldsW]);
    gload_lds16(pA0 + 32, &Ab[bfs][1][ldsW]);
    gload_lds16(pA1,      &Ab[bfs][0][ldsW + 4096]);
    gload_lds16(pA1 + 32, &Ab[bfs][1][ldsW + 4096]);
    gload_lds16(pBs,                &Bb[bfs][0][ldsW]);
    gload_lds16(pBs + 32,           &Bb[bfs][1][ldsW]);
    gload_lds16(pBs + bStride,      &Bb[bfs][0][ldsW + 4096]);
    gload_lds16(pBs + bStride + 32, &Bb[bfs][1][ldsW + 4096]);
    pBs += 64;
    if (++s_kc == KPC) { s_kc = 0; if (++s_tap == NTAPS) { s_tap = 0; ++s_cb; } }
  };

  auto ldA = [&](int buf, int ks, int mh, int i) {
    return ld_b128((const lds_bf16*)
        &Ab[buf][ks][((wr << 7) + (mh << 6) + (i << 4) + frow) * 32 + rdOff]);
  };
  auto ldB = [&](int buf, int ks, int j) {
    return ld_b128((const lds_bf16*)
        &Bb[buf][ks][((wc << 6) + (j << 4) + frow) * 32 + rdOff]);
  };

  stageTile(0);
  __syncthreads();

  bf16x8 a0[4], a1[4], b0[4], b1[4];

#pragma unroll 1
  for (int t = 0; t < NT; ++t) {
    const int buf = t & 1;
#pragma unroll
    for (int i = 0; i < 4; ++i) a0[i] = ldA(buf, ksA, 0, i);
#pragma unroll
    for (int j = 0; j < 4; ++j) b0[j] = ldB(buf, ksA, j);
    if (t + 1 < NT) stageTile(buf ^ 1);
#pragma unroll
    for (int i = 0; i < 4; ++i) a1[i] = ldA(buf, ksA, 1, i);
    asm volatile("s_waitcnt lgkmcnt(4)" ::: "memory");
    __builtin_amdgcn_sched_barrier(0);
    __builtin_amdgcn_s_setprio(1);
#pragma unroll
    for (int i = 0; i < 4; ++i)
#pragma unroll
      for (int j = 0; j < 4; ++j)
        acc[i][j] = __builtin_amdgcn_mfma_f32_16x16x32_bf16(a0[i], b0[j], acc[i][j], 0, 0, 0);
    __builtin_amdgcn_s_setprio(0);
#pragma unroll
    for (int i = 0; i < 4; ++i) a0[i] = ldA(buf, ksB, 0, i);
#pragma unroll
    for (int j = 0; j < 4; ++j) b1[j] = ldB(buf, ksB, j);
    asm volatile("s_waitcnt lgkmcnt(8)" ::: "memory");
    __builtin_amdgcn_sched_barrier(0);
    __builtin_amdgcn_s_setprio(1);
#pragma unroll
    for (int i = 0; i < 4; ++i)
#pragma unroll
      for (int j = 0; j < 4; ++j)
        acc[4 + i][j] = __builtin_amdgcn_mfma_f32_16x16x32_bf16(a1[i], b0[j], acc[4 + i][j], 0, 0, 0);
    __builtin_amdgcn_s_setprio(0);
#pragma unroll
    for (int i = 0; i < 4; ++i) a1[i] = ldA(buf, ksB, 1, i);
    asm volatile("s_waitcnt lgkmcnt(4)" ::: "memory");
    __builtin_amdgcn_sched_barrier(0);
    __builtin_amdgcn_s_setprio(1);
#pragma unroll
    for (int i = 0; i < 4; ++i)
#pragma unroll
      for (int j = 0; j < 4; ++j)
        acc[i][j] = __builtin_amdgcn_mfma_f32_16x16x32_bf16(a0[i], b1[j], acc[i][j], 0, 0, 0);
    __builtin_amdgcn_s_setprio(0);
    asm volatile("s_waitcnt lgkmcnt(0)" ::: "memory");
    __builtin_amdgcn_sched_barrier(0);
    __builtin_amdgcn_s_setprio(1);
#pragma unroll
    for (int i = 0; i < 4; ++i)
#pragma unroll
      for (int j = 0; j < 4; ++j)
        acc[4 + i][j] = __builtin_amdgcn_mfma_f32_16x16x32_bf16(a1[i], b1[j], acc[4 + i][j], 0, 0, 0);
    __builtin_amdgcn_s_setprio(0);
    __syncthreads();
  }

  // epilogue: fused maxpool2; C/D col=lane&15, row=(lane>>4)*4+reg
  const int colL = lane & 15, rq = (lane >> 4) << 2;
#pragma unroll
  for (int i = 0; i < 8; ++i) {
    int m = m0 + (wr << 7) + (i << 4) + rq;
    int n = m >> LOGP, p = m & (P - 1);
    bf16* orow = Out + n * snO + (p >> 1) * COt;
#pragma unroll
    for (int j = 0; j < 4; ++j) {
      int gco = co0 + (wc << 6) + (j << 4) + colL;
      float bv = bias[gco];
      orow[gco]       = (bf16)(fmaxf(acc[i][j][0], acc[i][j][1]) + bv);
      orow[COt + gco] = (bf16)(fmaxf(acc[i][j][2], acc[i][j][3]) + bv);
    }
  }
}

// ---------------- fused prep: weights + biases + cq/uu + batch cvt ----------
__global__ __launch_bounds__(256) void prep_all(
    const float* __restrict__ conv1_w, const float* __restrict__ conv2_w,
    const float* __restrict__ sa_wq, const float* __restrict__ sa_wk,
    const float* __restrict__ ca_wk, const float* __restrict__ dc1_w,
    const float* __restrict__ dc2_w, const float* __restrict__ sim1_w,
    const float* __restrict__ c1b, const float* __restrict__ c2b,
    const float* __restrict__ sabq, const float* __restrict__ sabk,
    const float* __restrict__ cabk, const float* __restrict__ d1b,
    const float* __restrict__ d2b,
    const float* __restrict__ c1, const float* __restrict__ c2,
    const float* __restrict__ ca_wq, const float* __restrict__ ca_bq,
    const float* __restrict__ sim2_w, const float* __restrict__ mlp_w,
    const float* __restrict__ batch, bf16* __restrict__ bb16,
    bf16* __restrict__ Bt1, bf16* __restrict__ Bt2, bf16* __restrict__ Bqkc,
    bf16* __restrict__ Btd1, bf16* __restrict__ Btd2, bf16* __restrict__ Bts1,
    float* __restrict__ bias, float* __restrict__ cq, float* __restrict__ uu)
{
  const int blk = blockIdx.x;
  if (blk >= 27492) {
    int idx = ((blk - 27492) * 256 + threadIdx.x) * 8;
    float4 a = *(const float4*)&batch[idx];
    float4 b = *(const float4*)&batch[idx + 4];
    bf16x8 v;
    v[0] = (bf16)a.x; v[1] = (bf16)a.y; v[2] = (bf16)a.z; v[3] = (bf16)a.w;
    v[4] = (bf16)b.x; v[5] = (bf16)b.y; v[6] = (bf16)b.z; v[7] = (bf16)b.w;
    *(bf16x8*)&bb16[idx] = v;
    return;
  }
  if (blk < 27468) {
    int idx = blk * 256 + threadIdx.x;
    if (idx < 3072) {
      if (idx < 2944) {
        float v;
        if (idx < 512)       v = c1b[idx];
        else if (idx < 768)  v = c2b[idx - 512];
        else if (idx < 1024) v = sabq[idx - 768];
        else if (idx < 1280) v = sabk[idx - 1024];
        else if (idx < 1536) v = cabk[idx - 1280];
        else if (idx < 2560) v = d1b[(idx - 1536) & 511];
        else if (idx < 2816) v = d2b[(idx - 2560) & 127];
        else                 v = 0.0f;
        bias[idx] = v;
      }
    } else if (idx < 2624512) {
      int i = idx - 3072;
      int co = i / 5120, r = i - co * 5120;
      int cb = r / 1280, r2 = r - cb * 1280;
      int tap = r2 >> 8, cl = r2 & 255;
      Bt1[i] = (bf16)conv1_w[co * 5120 + (cb * 256 + cl) * 5 + tap];
    } else if (idx < 3279872) {
      int i = idx - 2624512;
      int co = i / 2560, r = i - co * 2560;
      int cb = r / 1280, r2 = r - cb * 1280;
      int tap = r2 >> 8, cl = r2 & 255;
      Bt2[i] = (bf16)conv2_w[co * 2560 + (cb * 256 + cl) * 5 + tap];
    } else if (idx < 3476480) {
      int i = idx - 3279872;
      int co = i >> 8, ci = i & 255;
      float v;
      if (co < 256)      v = sa_wq[ci * 256 + co];
      else if (co < 512) v = sa_wk[ci * 256 + (co - 256)];
      else               v = ca_wk[ci * 256 + (co - 512)];
      Bqkc[i] = (bf16)v;
    } else if (idx < 6622208) {
      int i = idx - 3476480;
      int co = i / 3072, r = i - co * 3072;
      int cb = r / 768, r2 = r - cb * 768;
      int tap = r2 >> 8, cl = r2 & 255;
      int ci = cb * 256 + cl;
      int par = co >> 9, c = co & 511;
      int ki = -1;
      if (par == 0) { if (tap == 1) ki = 1; else if (tap == 0) ki = 3; }
      else          { if (tap == 2) ki = 0; else if (tap == 1) ki = 2; }
      Btd1[i] = (ki >= 0) ? (bf16)dc1_w[ci * 2048 + c * 4 + ki] : (bf16)0.0f;
    } else if (idx < 7015424) {
      int i = idx - 6622208;
      int co = i / 1536, r = i - co * 1536;
      int cb = r / 768, r2 = r - cb * 768;
      int tap = r2 >> 8, cl = r2 & 255;
      int ci = cb * 256 + cl;
      int par = co >> 7, c = co & 127;
      int ki = -1;
      if (par == 0) { if (tap == 1) ki = 1; else if (tap == 0) ki = 3; }
      else          { if (tap == 2) ki = 0; else if (tap == 1) ki = 2; }
      Btd2[i] = (ki >= 0) ? (bf16)dc2_w[ci * 512 + c * 4 + ki] : (bf16)0.0f;
    } else {
      int i = idx - 7015424;
      int co = i >> 7, ci = i & 127;
      Bts1[i] = (bf16)sim1_w[ci * 128 + co];
    }
  } else {
    int sub = blk - 27468;
    if (sub < 16) {
      int o = sub * 256 + threadIdx.x;
      int c = o >> 11, b = (o >> 8) & 7, h = o & 255;
      const float* cc = (c ? c2 : c1) + b * 300;
      float acc = ca_bq[h];
      for (int j = 0; j < 300; ++j)
        acc += cc[j] * ca_wq[j * 256 + h];
      cq[o] = acc;
    } else {
      int o = (sub - 16) * 256 + threadIdx.x;
      int c = o >> 10, b = (o >> 7) & 7, m = o & 127;
      const float* cc = (c ? c2 : c1) + b * 300;
      float acc = 0.0f;
      for (int j = 0; j < 300; ++j)
        acc += cc[j] * sim2_w[j * 128 + m];
      uu[o] = acc * mlp_w[m];
    }
  }
}

// ---------------- fused additive attention (one block per n) ----------------
__global__ __launch_bounds__(256) void kattn(
    const bf16* __restrict__ tmp2, const bf16* __restrict__ qkc,
    const float* __restrict__ sa_v, const float* __restrict__ sa_vb,
    const float* __restrict__ ca_v, const float* __restrict__ ca_vb,
    const float* __restrict__ cq, const int* __restrict__ seg,
    bf16* __restrict__ ar)
{
  const int n = blockIdx.x, tid = threadIdx.x;
  __shared__ __align__(16) bf16 t2[32 * 264];
  __shared__ __align__(16) bf16 bufA[32 * 264];
  __shared__ __align__(16) bf16 bufB[32 * 264];
  __shared__ float sv_s[256], cv_s[256];
  __shared__ float sbc[66];
  __shared__ float sbs[32 * 33];
  const int sl = seg[n];

#pragma unroll
  for (int rr = 0; rr < 4; ++rr) {
    int q = tid + (rr << 8);
    int k = q >> 5, c8 = (q & 31) << 3;
    *(uint4*)&t2[k * 264 + c8]   = *(const uint4*)&tmp2[n * 8192 + k * 256 + c8];
    *(uint4*)&bufA[k * 264 + c8] = *(const uint4*)&qkc[n * 24576 + k * 768 + 512 + c8];
  }
  sv_s[tid] = sa_v[tid];
  cv_s[tid] = ca_v[tid];
  __syncthreads();

  if (tid < 64) {
    int c = tid >> 5, k = tid & 31;
    const float* cqr = cq + (c * 8 + (n >> 5)) * 256;
    float acc = 0.0f;
    for (int h = 0; h < 256; ++h)
      acc += tanh_fast(cqr[h] + (float)bufA[k * 264 + h]) * cv_s[h];
    float sc = acc + ca_vb[0];
    sbc[c * 33 + k] = (sl > (k << 2)) ? sc : -1e9f;
  }
  __syncthreads();

#pragma unroll
  for (int rr = 0; rr < 4; ++rr) {
    int q = tid + (rr << 8);
    int k = q >> 5, c8 = (q & 31) << 3;
    *(uint4*)&bufB[k * 264 + c8] = *(const uint4*)&qkc[n * 24576 + k * 768 + c8];
    *(uint4*)&bufA[k * 264 + c8] = *(const uint4*)&qkc[n * 24576 + k * 768 + 256 + c8];
  }
  if (tid < 2) {
    float* row = &sbc[tid * 33];
    float mx = -1e30f;
    for (int k = 0; k < 32; ++k) mx = fmaxf(mx, row[k]);
    float sum = 0.0f;
    for (int k = 0; k < 32; ++k) { float e = __expf(row[k] - mx); row[k] = e; sum += e; }
    float inv = 1.0f / sum;
    for (int k = 0; k < 32; ++k) row[k] *= inv;
  }
  __syncthreads();

  {
    int col = tid;
    float rr0 = 0.0f, rr1 = 0.0f;
    for (int k = 0; k < 32; ++k) {
      float tv = (float)t2[k * 264 + col];
      rr0 += sbc[k] * tv;
      rr1 += sbc[33 + k] * tv;
    }
    bf16 b0 = (bf16)rr0, b1 = (bf16)rr1;
    bf16* arn = ar + n * 32768;
    for (int q = 0; q < 32; ++q) {
      arn[q * 1024 + col]       = t2[q * 264 + col];
      arn[q * 1024 + 512 + col] = b0;
      arn[q * 1024 + 768 + col] = b1;
    }
  }
  {
    float svb = sa_vb[0];
#pragma unroll
    for (int rr = 0; rr < 4; ++rr) {
      int id = tid + (rr << 8);
      int q = id >> 5, k = id & 31;
      float acc = 0.0f;
      for (int h = 0; h < 256; ++h)
        acc += tanh_fast((float)bufB[q * 264 + h] + (float)bufA[k * 264 + h]) * sv_s[h];
      float sc = acc + svb;
      sbs[q * 33 + k] = (sl > (k << 2)) ? sc : -1e9f;
    }
  }
  __syncthreads();

  if (tid < 32) {
    float* row = &sbs[tid * 33];
    float mx = -1e30f;
    for (int k = 0; k < 32; ++k) mx = fmaxf(mx, row[k]);
    float sum = 0.0f;
    for (int k = 0; k < 32; ++k) { float e = __expf(row[k] - mx); row[k] = e; sum += e; }
    float inv = 1.0f / sum;
    for (int k = 0; k < 32; ++k) row[k] *= inv;
  }
  __syncthreads();

  {
    int col = tid;
    bf16* arn = ar + n * 32768;
    for (int q = 0; q < 32; ++q) {
      float acc = 0.0f;
      for (int k = 0; k < 32; ++k)
        acc += sbs[q * 33 + k] * (float)t2[k * 264 + col];
      arn[q * 1024 + 256 + col] = (bf16)acc;
    }
  }
}

// ---------------- launch ----------------
extern "C" void kernel_launch(void* const* d_in, const int* in_sizes, int n_in,
                              void* d_out, int out_size, void* d_ws, size_t ws_size,
                              hipStream_t stream) {
  const float* batch    = (const float*)d_in[0];
  const float* concept1 = (const float*)d_in[1];
  const float* concept2 = (const float*)d_in[2];
  const int*   seg      = (const int*)d_in[3];
  const float* conv1_w  = (const float*)d_in[4];
  const float* conv1_b  = (const float*)d_in[5];
  const float* conv2_w  = (const float*)d_in[6];
  const float* conv2_b  = (const float*)d_in[7];
  const float* sa_wq    = (const float*)d_in[8];
  const float* sa_bq    = (const float*)d_in[9];
  const float* sa_wk    = (const float*)d_in[10];
  const float* sa_bk    = (const float*)d_in[11];
  const float* sa_v     = (const float*)d_in[12];
  const float* sa_vb    = (const float*)d_in[13];
  const float* ca_wq    = (const float*)d_in[14];
  const float* ca_bq    = (const float*)d_in[15];
  const float* ca_wk    = (const float*)d_in[16];
  const float* ca_bk    = (const float*)d_in[17];
  const float* ca_v     = (const float*)d_in[18];
  const float* ca_vb    = (const float*)d_in[19];
  const float* dc1_w    = (const float*)d_in[20];
  const float* dc1_b    = (const float*)d_in[21];
  const float* dc2_w    = (const float*)d_in[22];
  const float* dc2_b    = (const float*)d_in[23];
  const float* sim1_w   = (const float*)d_in[24];
  const float* sim2_w   = (const float*)d_in[25];
  const float* mlp_w    = (const float*)d_in[26];
  const float* mlp_b    = (const float*)d_in[27];

  char* ws = (char*)d_ws;
  bf16* bb16  = (bf16*)(ws + 0);
  bf16* qkcb  = (bf16*)(ws + 0);
  bf16* arb   = (bf16*)(ws + 12582912);
  bf16* d1    = (bf16*)(ws + 29360128);
  bf16* rbuf  = (bf16*)(ws + 46137344);
  bf16* t1    = (bf16*)(ws + 67108864);
  bf16* tmp2b = (bf16*)(ws + 83886080);
  bf16* Bt1   = (bf16*)(ws + 88080384);
  bf16* Bt2   = (bf16*)(ws + 93323264);
  bf16* Bqkc  = (bf16*)(ws + 94633984);
  bf16* Btd1  = (bf16*)(ws + 95027200);
  bf16* Btd2  = (bf16*)(ws + 101318656);
  bf16* Bts1  = (bf16*)(ws + 102105088);
  float* biasall = (float*)(ws + 102137856);
  float* cqb  = (float*)(ws + 102149632);
  float* uub  = (float*)(ws + 102166016);
  const bf16* zp = (const bf16*)(biasall + 2816);  // 128 f32 zeros = 256 bf16 zeros
  float* outp = (float*)d_out;

  prep_all<<<43876, 256, 0, stream>>>(
      conv1_w, conv2_w, sa_wq, sa_wk, ca_wk, dc1_w, dc2_w, sim1_w,
      conv1_b, conv2_b, sa_bq, sa_bk, ca_bk, dc1_b, dc2_b,
      concept1, concept2, ca_wq, ca_bq, sim2_w, mlp_w,
      batch, bb16,
      Bt1, Bt2, Bqkc, Btd1, Btd2, Bts1, biasall, cqb, uub);

  // conv1 + pool: 256^2-tile pipelined, wave-staggered -> t1 [256][64][512]
  gemm8_pool<7, 10, -2, 5, 4, 256><<<dim3(128, 2), 512, 0, stream>>>(
      bb16, Bt1, biasall + 0, t1, zp, 131072, 5120, 512, 32768);

  // conv2 + pool: pipelined 128^2 -> tmp2 [256][32][256]
  gemm_tap<1><<<dim3(128, 2), 256, 0, stream>>>(
      t1, Bt2, biasall + 512, tmp2b, zp, 32768, 6, 9, -2, 5, 2, 256, 4, 2560, 256, 8192,
      nullptr, nullptr, nullptr);

  // fused q/k/ck projection -> qkc [256][32][768]
  gemm_tap<0><<<dim3(64, 6), 256, 0, stream>>>(
      tmp2b, Bqkc, biasall + 768, qkcb, zp, 8192, 5, 8, 0, 1, 1, 256, 4, 256, 768, 24576,
      nullptr, nullptr, nullptr);

  // attention -> ar [256][32][1024]
  kattn<<<256, 256, 0, stream>>>(tmp2b, qkcb, sa_v, sa_vb, ca_v, ca_vb, cqb, seg, arb);

  // deconv1 -> d1 [256][64][1024] (parity-interleaved)
  gemm_tap<0><<<dim3(64, 8), 256, 0, stream>>>(
      arb, Btd1, biasall + 1536, d1, zp, 32768, 5, 10, -1, 3, 4, 256, 4, 3072, 1024, 32768,
      nullptr, nullptr, nullptr);

  // deconv2 -> rbuf [256][64][256] (parity-interleaved)
  gemm_tap<0><<<dim3(128, 2), 256, 0, stream>>>(
      d1, Btd2, biasall + 2560, rbuf, zp, 32768, 6, 9, -1, 3, 2, 256, 4, 1536, 256, 16384,
      nullptr, nullptr, nullptr);

  // sim1 + fused score -> out (fp32, both concepts)
  gemm_tap<2><<<dim3(256, 1), 256, 0, stream>>>(
      rbuf, Bts1, biasall + 2816, nullptr, zp, 16384, 7, 7, 0, 1, 1, 128, 2, 128, 128, 16384,
      uub, mlp_b, outp);
}